// Round 1
// baseline (151.935 us; speedup 1.0000x reference)
//
#include <hip/hip_runtime.h>

#define Nn 2048
#define FIN 512
#define FO 64
#define SHIFT 20.0f
#define NJT 32
#define JR (Nn / NJT)   // 64 j per block -> single chunk of 64 (jc loop eliminated)
#define LS 66           // LDS row stride: even (8B-aligned float2 rows), 4-way worst bank aliasing
#define PTS 68          // pT row stride: 68*4B = 272B -> 16B-aligned float4 rows
#define ZTOT (Nn * FO + Nn)   // osum + lsum floats, contiguous = 133120

// ---------------- K1: h = x @ W  (proven) + fused zeroing of osum/lsum ----------------
__global__ __launch_bounds__(256) void gat_xw(const float* __restrict__ x,
                                              const float* __restrict__ W,
                                              float* __restrict__ h,
                                              float* __restrict__ z) {
    // fused accumulator zeroing: 1024 blocks x 256 thr = 262144 >= ZTOT
    const int gt = blockIdx.x * 256 + threadIdx.x;
    if (gt < ZTOT) z[gt] = 0.f;

    __shared__ float part[2][2][FO];
    const int wave = threadIdx.x >> 6;
    const int lane = threadIdx.x & 63;
    const int rs = wave >> 1;
    const int kh = wave & 1;
    int row = blockIdx.x * 2 + rs;
    row = __builtin_amdgcn_readfirstlane(row);
    const float* xr = x + (size_t)row * FIN + kh * (FIN / 2);
    const float* Wp = W + (size_t)kh * (FIN / 2) * FO;
    float acc = 0.f;
#pragma unroll 2
    for (int k = 0; k < FIN / 2; k += 8) {
        float4 xa = *(const float4*)(xr + k);
        float4 xb = *(const float4*)(xr + k + 4);
        acc = fmaf(xa.x, Wp[(k + 0) * FO + lane], acc);
        acc = fmaf(xa.y, Wp[(k + 1) * FO + lane], acc);
        acc = fmaf(xa.z, Wp[(k + 2) * FO + lane], acc);
        acc = fmaf(xa.w, Wp[(k + 3) * FO + lane], acc);
        acc = fmaf(xb.x, Wp[(k + 4) * FO + lane], acc);
        acc = fmaf(xb.y, Wp[(k + 5) * FO + lane], acc);
        acc = fmaf(xb.z, Wp[(k + 6) * FO + lane], acc);
        acc = fmaf(xb.w, Wp[(k + 7) * FO + lane], acc);
    }
    part[rs][kh][lane] = acc;
    __syncthreads();
    if (threadIdx.x < 128) {
        const int r2 = threadIdx.x >> 6;
        const int l2 = threadIdx.x & 63;
        h[((size_t)blockIdx.x * 2 + r2) * FO + l2] = part[r2][0][l2] + part[r2][1][l2];
    }
}

// ---------------- K2: register-tiled e + fixed-shift p + fused PV, atomic accumulation ----------------
// Block = 256 thr = 4 waves = 64-i tile x one 64-j tile (NJT=32 j-tiles -> 1024 blocks = 4/CU).
// LDS shrunk to 34.6 KB by overlaying pT on hi (hi is dead after the e-phase since there is
// exactly one j-chunk per block) -> 4 blocks/CU resident (was 2).
// e-phase: wave = 16i x 64j; lane (li=lane&3, lj=lane>>2) owns 4i x 4j.
// PV-phase: lane re-mapped to 4i x 4f through pT slice (wave-private columns).
__global__ __launch_bounds__(256, 4) void gat_attn3(const float* __restrict__ h,
                                                    const int* __restrict__ adj,
                                                    const float* __restrict__ a,
                                                    float* __restrict__ osum,
                                                    float* __restrict__ lsum) {
    __shared__ float up[64 * PTS];     // union: hi_s (stride LS, 64*66 used) / pT_s (stride PTS)
    __shared__ float hj_s[64 * LS];
    __shared__ float a_s[FO];
    float* hi_s = up;
    float* pT_s = up;

    const int tid = threadIdx.x;
    const int w = tid >> 6;
    const int lane = tid & 63;
    const int li = lane & 3;
    const int lj = lane >> 2;
    const int it = blockIdx.x >> 5;          // 0..31
    const int jt = blockIdx.x & (NJT - 1);   // 0..31
    const int ib = it * 64;
    const int jb = jt * JR;
    const int iw = w * 16;

    // stage hi and hj tiles (64 x 64 each)
    for (int g4 = tid; g4 < 1024; g4 += 256) {
        float4 v = *(const float4*)(h + (size_t)ib * FO + (size_t)g4 * 4);
        float* d = &hi_s[(g4 >> 4) * LS + (g4 & 15) * 4];
        *(float2*)d = make_float2(v.x, v.y);
        *(float2*)(d + 2) = make_float2(v.z, v.w);
        float4 u = *(const float4*)(h + (size_t)jb * FO + (size_t)g4 * 4);
        float* e2 = &hj_s[(g4 >> 4) * LS + (g4 & 15) * 4];
        *(float2*)e2 = make_float2(u.x, u.y);
        *(float2*)(e2 + 2) = make_float2(u.z, u.w);
    }
    if (tid < FO) a_s[tid] = a[tid];
    __syncthreads();

    // adjacency for this lane's 4x4 (16B-aligned: col offset multiple of 4 ints)
    int4 am[4];
#pragma unroll
    for (int di = 0; di < 4; di++)
        am[di] = *(const int4*)(adj + (size_t)(ib + iw + 4 * li + di) * Nn + (jb + 4 * lj));

    float pv[4][4];
    float ls[4];
#pragma unroll
    for (int u = 0; u < 4; u++) {
        ls[u] = 0.f;
#pragma unroll
        for (int v2 = 0; v2 < 4; v2++) pv[u][v2] = 0.f;
    }

    // ---- e-phase: e[di][dj] = sum_f a_f * |hi - hj| ----
    float e[4][4];
#pragma unroll
    for (int di = 0; di < 4; di++)
#pragma unroll
        for (int dj = 0; dj < 4; dj++) e[di][dj] = 0.f;

#pragma unroll 4
    for (int f = 0; f < FO; f += 2) {
        const float2 av = *(const float2*)&a_s[f];
        float2 hi[4], hj[4];
#pragma unroll
        for (int d = 0; d < 4; d++) {
            hi[d] = *(const float2*)&hi_s[(iw + 4 * li + d) * LS + f];
            hj[d] = *(const float2*)&hj_s[(4 * lj + d) * LS + f];
        }
#pragma unroll
        for (int di = 0; di < 4; di++)
#pragma unroll
            for (int dj = 0; dj < 4; dj++) {
                e[di][dj] = fmaf(fabsf(hi[di].x - hj[dj].x), av.x, e[di][dj]);
                e[di][dj] = fmaf(fabsf(hi[di].y - hj[dj].y), av.y, e[di][dj]);
            }
    }

    // ---- p = adj ? exp(relu(e) - SHIFT) : 0  (shift-invariant softmax, exact) ----
#pragma unroll
    for (int di = 0; di < 4; di++) {
        const int* ap = (const int*)&am[di];
#pragma unroll
        for (int dj = 0; dj < 4; dj++) {
            const float p = (ap[dj] > 0) ? __expf(fmaxf(e[di][dj], 0.f) - SHIFT) : 0.f;
            e[di][dj] = p;
            ls[di] += p;
        }
    }

    // all waves must be done reading hi_s before pT overwrites it (union)
    __syncthreads();

    // transpose p through pT (wave-private column slice [iw, iw+16))
#pragma unroll
    for (int dj = 0; dj < 4; dj++) {
        *(float4*)&pT_s[(4 * lj + dj) * PTS + iw + 4 * li] =
            make_float4(e[0][dj], e[1][dj], e[2][dj], e[3][dj]);
    }
    __syncthreads();   // defensive: order pT writes before PV reads explicitly

    // ---- PV: lane -> (4i x 4f): i = iw+4*li+di, f = 4*lj+v ----
#pragma unroll 4
    for (int j = 0; j < 64; j++) {
        const float4 pj = *(const float4*)&pT_s[j * PTS + iw + 4 * li];
        const float2 h0 = *(const float2*)&hj_s[j * LS + 4 * lj];
        const float2 h1 = *(const float2*)&hj_s[j * LS + 4 * lj + 2];
        pv[0][0] = fmaf(pj.x, h0.x, pv[0][0]);
        pv[0][1] = fmaf(pj.x, h0.y, pv[0][1]);
        pv[0][2] = fmaf(pj.x, h1.x, pv[0][2]);
        pv[0][3] = fmaf(pj.x, h1.y, pv[0][3]);
        pv[1][0] = fmaf(pj.y, h0.x, pv[1][0]);
        pv[1][1] = fmaf(pj.y, h0.y, pv[1][1]);
        pv[1][2] = fmaf(pj.y, h1.x, pv[1][2]);
        pv[1][3] = fmaf(pj.y, h1.y, pv[1][3]);
        pv[2][0] = fmaf(pj.z, h0.x, pv[2][0]);
        pv[2][1] = fmaf(pj.z, h0.y, pv[2][1]);
        pv[2][2] = fmaf(pj.z, h1.x, pv[2][2]);
        pv[2][3] = fmaf(pj.z, h1.y, pv[2][3]);
        pv[3][0] = fmaf(pj.w, h0.x, pv[3][0]);
        pv[3][1] = fmaf(pj.w, h0.y, pv[3][1]);
        pv[3][2] = fmaf(pj.w, h1.x, pv[3][2]);
        pv[3][3] = fmaf(pj.w, h1.y, pv[3][3]);
    }

    // ---- epilogue: reduce l over lj lanes, then atomic-accumulate ----
#pragma unroll
    for (int di = 0; di < 4; di++) {
        float v = ls[di];
        v += __shfl_xor(v, 4, 64);
        v += __shfl_xor(v, 8, 64);
        v += __shfl_xor(v, 16, 64);
        v += __shfl_xor(v, 32, 64);
        ls[di] = v;
    }
    if (lj == 0) {
#pragma unroll
        for (int di = 0; di < 4; di++)
            atomicAdd(&lsum[ib + iw + 4 * li + di], ls[di]);
    }
#pragma unroll
    for (int di = 0; di < 4; di++) {
#pragma unroll
        for (int v2 = 0; v2 < 4; v2++)
            atomicAdd(&osum[(size_t)(ib + iw + 4 * li + di) * FO + 4 * lj + v2], pv[di][v2]);
    }
}

// ---------------- K3: out = relu(osum / lsum) ----------------
__global__ __launch_bounds__(256) void gat_fin(const float* __restrict__ osum,
                                               const float* __restrict__ lsum,
                                               float* __restrict__ out) {
    const int t = blockIdx.x * 256 + threadIdx.x;   // grid 512 -> 131072
    out[t] = fmaxf(osum[t] / lsum[t >> 6], 0.f);
}

extern "C" void kernel_launch(void* const* d_in, const int* in_sizes, int n_in,
                              void* d_out, int out_size, void* d_ws, size_t ws_size,
                              hipStream_t stream) {
    const float* x   = (const float*)d_in[0];
    const int*   adj = (const int*)d_in[1];
    const float* W   = (const float*)d_in[2];
    const float* a   = (const float*)d_in[3];
    float* out = (float*)d_out;

    float* h    = (float*)d_ws;                      // 131072 floats
    float* osum = h + (size_t)Nn * FO;               // 131072 floats
    float* lsum = osum + (size_t)Nn * FO;            // 2048 floats
    // total ws: 1,056,768 B — within the proven envelope

    gat_xw<<<dim3(1024), dim3(256), 0, stream>>>(x, W, h, osum);   // also zeros osum+lsum
    gat_attn3<<<dim3(32 * NJT), dim3(256), 0, stream>>>(h, adj, a, osum, lsum);
    gat_fin<<<dim3(512), dim3(256), 0, stream>>>(osum, lsum, out);
}

// Round 2
// 118.765 us; speedup vs baseline: 1.2793x; 1.2793x over previous
//
#include <hip/hip_runtime.h>

#define Nn 2048
#define FIN 512
#define FO 64
#define SHIFT 20.0f
#define NJT 32
#define JR (Nn / NJT)   // 64 j per block -> single chunk (jc loop eliminated)
#define LS 66           // LDS row stride: even (8B-aligned float2 rows)
#define PTS 68          // pT row stride: 68*4B = 272B -> 16B-aligned float4 rows
#define ZTOT (Nn * FO + Nn)   // osum + lsum floats (fallback path only)

// ---------------- K1: h = x @ W  (proven) + optional zeroing (fallback path) ----------------
__global__ __launch_bounds__(256) void gat_xw(const float* __restrict__ x,
                                              const float* __restrict__ W,
                                              float* __restrict__ h,
                                              float* __restrict__ z) {
    const int gt = blockIdx.x * 256 + threadIdx.x;
    if (z != nullptr && gt < ZTOT) z[gt] = 0.f;

    __shared__ float part[2][2][FO];
    const int wave = threadIdx.x >> 6;
    const int lane = threadIdx.x & 63;
    const int rs = wave >> 1;
    const int kh = wave & 1;
    int row = blockIdx.x * 2 + rs;
    row = __builtin_amdgcn_readfirstlane(row);
    const float* xr = x + (size_t)row * FIN + kh * (FIN / 2);
    const float* Wp = W + (size_t)kh * (FIN / 2) * FO;
    float acc = 0.f;
#pragma unroll 2
    for (int k = 0; k < FIN / 2; k += 8) {
        float4 xa = *(const float4*)(xr + k);
        float4 xb = *(const float4*)(xr + k + 4);
        acc = fmaf(xa.x, Wp[(k + 0) * FO + lane], acc);
        acc = fmaf(xa.y, Wp[(k + 1) * FO + lane], acc);
        acc = fmaf(xa.z, Wp[(k + 2) * FO + lane], acc);
        acc = fmaf(xa.w, Wp[(k + 3) * FO + lane], acc);
        acc = fmaf(xb.x, Wp[(k + 4) * FO + lane], acc);
        acc = fmaf(xb.y, Wp[(k + 5) * FO + lane], acc);
        acc = fmaf(xb.z, Wp[(k + 6) * FO + lane], acc);
        acc = fmaf(xb.w, Wp[(k + 7) * FO + lane], acc);
    }
    part[rs][kh][lane] = acc;
    __syncthreads();
    if (threadIdx.x < 128) {
        const int r2 = threadIdx.x >> 6;
        const int l2 = threadIdx.x & 63;
        h[((size_t)blockIdx.x * 2 + r2) * FO + l2] = part[r2][0][l2] + part[r2][1][l2];
    }
}

// ---------------- K2: register-tiled e + fixed-shift p + fused PV ----------------
// Block = 256 thr = 4 waves = 64-i tile x one 64-j tile (NJT=32 -> 1024 blocks = 4/CU).
// ATOMIC=false: each block stores its private partial tile with plain float4 stores
//   (po[jt][i][f], pl[jt][i]) -- no L2 RMW serialization, fast block retire.
// ATOMIC=true : round-1 atomicAdd path (workspace-constrained fallback).
template <bool ATOMIC>
__global__ __launch_bounds__(256, 4) void gat_attn(const float* __restrict__ h,
                                                   const int* __restrict__ adj,
                                                   const float* __restrict__ a,
                                                   float* __restrict__ po,
                                                   float* __restrict__ pl) {
    __shared__ float up[64 * PTS];     // union: hi_s (stride LS) / pT_s (stride PTS)
    __shared__ float hj_s[64 * LS];
    __shared__ float a_s[FO];
    float* hi_s = up;
    float* pT_s = up;

    const int tid = threadIdx.x;
    const int w = tid >> 6;
    const int lane = tid & 63;
    const int li = lane & 3;
    const int lj = lane >> 2;
    const int it = blockIdx.x >> 5;          // 0..31
    const int jt = blockIdx.x & (NJT - 1);   // 0..31
    const int ib = it * 64;
    const int jb = jt * JR;
    const int iw = w * 16;

    // stage hi and hj tiles (64 x 64 each)
    for (int g4 = tid; g4 < 1024; g4 += 256) {
        float4 v = *(const float4*)(h + (size_t)ib * FO + (size_t)g4 * 4);
        float* d = &hi_s[(g4 >> 4) * LS + (g4 & 15) * 4];
        *(float2*)d = make_float2(v.x, v.y);
        *(float2*)(d + 2) = make_float2(v.z, v.w);
        float4 u = *(const float4*)(h + (size_t)jb * FO + (size_t)g4 * 4);
        float* e2 = &hj_s[(g4 >> 4) * LS + (g4 & 15) * 4];
        *(float2*)e2 = make_float2(u.x, u.y);
        *(float2*)(e2 + 2) = make_float2(u.z, u.w);
    }
    if (tid < FO) a_s[tid] = a[tid];
    __syncthreads();

    // adjacency for this lane's 4x4 (16B-aligned: col offset multiple of 4 ints)
    int4 am[4];
#pragma unroll
    for (int di = 0; di < 4; di++)
        am[di] = *(const int4*)(adj + (size_t)(ib + iw + 4 * li + di) * Nn + (jb + 4 * lj));

    float pv[4][4];
    float ls[4];
#pragma unroll
    for (int u = 0; u < 4; u++) {
        ls[u] = 0.f;
#pragma unroll
        for (int v2 = 0; v2 < 4; v2++) pv[u][v2] = 0.f;
    }

    // ---- e-phase: e[di][dj] = sum_f a_f * |hi - hj| ----
    float e[4][4];
#pragma unroll
    for (int di = 0; di < 4; di++)
#pragma unroll
        for (int dj = 0; dj < 4; dj++) e[di][dj] = 0.f;

#pragma unroll 4
    for (int f = 0; f < FO; f += 2) {
        const float2 av = *(const float2*)&a_s[f];
        float2 hi[4], hj[4];
#pragma unroll
        for (int d = 0; d < 4; d++) {
            hi[d] = *(const float2*)&hi_s[(iw + 4 * li + d) * LS + f];
            hj[d] = *(const float2*)&hj_s[(4 * lj + d) * LS + f];
        }
#pragma unroll
        for (int di = 0; di < 4; di++)
#pragma unroll
            for (int dj = 0; dj < 4; dj++) {
                e[di][dj] = fmaf(fabsf(hi[di].x - hj[dj].x), av.x, e[di][dj]);
                e[di][dj] = fmaf(fabsf(hi[di].y - hj[dj].y), av.y, e[di][dj]);
            }
    }

    // ---- p = adj ? exp(relu(e) - SHIFT) : 0  (shift-invariant softmax, exact) ----
#pragma unroll
    for (int di = 0; di < 4; di++) {
        const int* ap = (const int*)&am[di];
#pragma unroll
        for (int dj = 0; dj < 4; dj++) {
            const float p = (ap[dj] > 0) ? __expf(fmaxf(e[di][dj], 0.f) - SHIFT) : 0.f;
            e[di][dj] = p;
            ls[di] += p;
        }
    }

    // all waves must be done reading hi_s before pT overwrites it (union)
    __syncthreads();

    // transpose p through pT (wave-private column slice [iw, iw+16))
#pragma unroll
    for (int dj = 0; dj < 4; dj++) {
        *(float4*)&pT_s[(4 * lj + dj) * PTS + iw + 4 * li] =
            make_float4(e[0][dj], e[1][dj], e[2][dj], e[3][dj]);
    }
    __syncthreads();   // order pT writes before PV reads

    // ---- PV: lane -> (4i x 4f): i = iw+4*li+di, f = 4*lj+v ----
#pragma unroll 4
    for (int j = 0; j < 64; j++) {
        const float4 pj = *(const float4*)&pT_s[j * PTS + iw + 4 * li];
        const float2 h0 = *(const float2*)&hj_s[j * LS + 4 * lj];
        const float2 h1 = *(const float2*)&hj_s[j * LS + 4 * lj + 2];
        pv[0][0] = fmaf(pj.x, h0.x, pv[0][0]);
        pv[0][1] = fmaf(pj.x, h0.y, pv[0][1]);
        pv[0][2] = fmaf(pj.x, h1.x, pv[0][2]);
        pv[0][3] = fmaf(pj.x, h1.y, pv[0][3]);
        pv[1][0] = fmaf(pj.y, h0.x, pv[1][0]);
        pv[1][1] = fmaf(pj.y, h0.y, pv[1][1]);
        pv[1][2] = fmaf(pj.y, h1.x, pv[1][2]);
        pv[1][3] = fmaf(pj.y, h1.y, pv[1][3]);
        pv[2][0] = fmaf(pj.z, h0.x, pv[2][0]);
        pv[2][1] = fmaf(pj.z, h0.y, pv[2][1]);
        pv[2][2] = fmaf(pj.z, h1.x, pv[2][2]);
        pv[2][3] = fmaf(pj.z, h1.y, pv[2][3]);
        pv[3][0] = fmaf(pj.w, h0.x, pv[3][0]);
        pv[3][1] = fmaf(pj.w, h0.y, pv[3][1]);
        pv[3][2] = fmaf(pj.w, h1.x, pv[3][2]);
        pv[3][3] = fmaf(pj.w, h1.y, pv[3][3]);
    }

    // ---- epilogue: reduce l over lj lanes ----
#pragma unroll
    for (int di = 0; di < 4; di++) {
        float v = ls[di];
        v += __shfl_xor(v, 4, 64);
        v += __shfl_xor(v, 8, 64);
        v += __shfl_xor(v, 16, 64);
        v += __shfl_xor(v, 32, 64);
        ls[di] = v;
    }

    if constexpr (!ATOMIC) {
        // private partial slice: po[jt][i][f], pl[jt][i] -- plain coalesced stores
        if (lj == 0) {
#pragma unroll
            for (int di = 0; di < 4; di++)
                pl[(size_t)jt * Nn + (ib + iw + 4 * li + di)] = ls[di];
        }
#pragma unroll
        for (int di = 0; di < 4; di++)
            *(float4*)&po[((size_t)jt * Nn + (ib + iw + 4 * li + di)) * FO + 4 * lj] =
                make_float4(pv[di][0], pv[di][1], pv[di][2], pv[di][3]);
    } else {
        if (lj == 0) {
#pragma unroll
            for (int di = 0; di < 4; di++)
                atomicAdd(&pl[ib + iw + 4 * li + di], ls[di]);
        }
#pragma unroll
        for (int di = 0; di < 4; di++) {
#pragma unroll
            for (int v2 = 0; v2 < 4; v2++)
                atomicAdd(&po[(size_t)(ib + iw + 4 * li + di) * FO + 4 * lj + v2], pv[di][v2]);
        }
    }
}

// ---------------- K3: out = relu(sum_jt po / sum_jt pl)  (fuses old gat_fin) ----------------
__global__ __launch_bounds__(256) void gat_reduce(const float* __restrict__ po,
                                                  const float* __restrict__ pl,
                                                  float* __restrict__ out) {
    const int t = blockIdx.x * 256 + threadIdx.x;   // grid 512 -> 131072 = Nn*FO
    const int i = t >> 6;
    float s = 0.f;
#pragma unroll
    for (int p = 0; p < NJT; p++) s += po[(size_t)p * (Nn * FO) + t];
    float l = 0.f;
#pragma unroll
    for (int p = 0; p < NJT; p++) l += pl[p * Nn + i];   // wave-uniform addr -> broadcast
    out[t] = fmaxf(s / l, 0.f);
}

// ---------------- fallback K3: out = relu(osum / lsum) ----------------
__global__ __launch_bounds__(256) void gat_fin(const float* __restrict__ osum,
                                               const float* __restrict__ lsum,
                                               float* __restrict__ out) {
    const int t = blockIdx.x * 256 + threadIdx.x;
    out[t] = fmaxf(osum[t] / lsum[t >> 6], 0.f);
}

extern "C" void kernel_launch(void* const* d_in, const int* in_sizes, int n_in,
                              void* d_out, int out_size, void* d_ws, size_t ws_size,
                              hipStream_t stream) {
    const float* x   = (const float*)d_in[0];
    const int*   adj = (const int*)d_in[1];
    const float* W   = (const float*)d_in[2];
    const float* a   = (const float*)d_in[3];
    float* out = (float*)d_out;

    float* h = (float*)d_ws;                                   // Nn*FO floats
    const size_t need = ((size_t)Nn * FO + (size_t)NJT * Nn * FO + (size_t)NJT * Nn) * 4;

    if (ws_size >= need) {
        // no-atomic path: private partials + reduction
        float* po = h + (size_t)Nn * FO;                       // NJT*Nn*FO floats
        float* pl = po + (size_t)NJT * Nn * FO;                // NJT*Nn floats
        gat_xw<<<dim3(1024), dim3(256), 0, stream>>>(x, W, h, nullptr);
        gat_attn<false><<<dim3(32 * NJT), dim3(256), 0, stream>>>(h, adj, a, po, pl);
        gat_reduce<<<dim3(512), dim3(256), 0, stream>>>(po, pl, out);
    } else {
        // fallback: round-1 atomic accumulation (1.06 MB workspace)
        float* osum = h + (size_t)Nn * FO;
        float* lsum = osum + (size_t)Nn * FO;
        gat_xw<<<dim3(1024), dim3(256), 0, stream>>>(x, W, h, osum);   // zeros osum+lsum
        gat_attn<true><<<dim3(32 * NJT), dim3(256), 0, stream>>>(h, adj, a, osum, lsum);
        gat_fin<<<dim3(512), dim3(256), 0, stream>>>(osum, lsum, out);
    }
}

// Round 4
// 118.350 us; speedup vs baseline: 1.2838x; 1.0035x over previous
//
#include <hip/hip_runtime.h>

#define Nn 2048
#define FIN 512
#define FO 64
#define SHIFT 20.0f
#define NJT 32
#define JR (Nn / NJT)   // 64 j per block -> single chunk
#define HS 68           // hi/hj row stride: 272B rows -> 16B-aligned float4 blocks
#define PTS 68          // pT row stride: 272B -> 16B-aligned float4 rows
#define ZTOT (Nn * FO + Nn)   // osum + lsum floats (fallback path only)

// f4-block XOR swizzle: row r, float col f (f%4==0 at all call sites).
// Swizzling the f4-index with (r>>2)&15 spreads the 16 distinct-row accesses of the
// e-phase (rows 4*lj+d) and the 16 distinct-col accesses of PV (cols 4*lj) across
// 8 bank-start groups x 2-way = exact conflict floor, while keeping 16B contiguity.
#define HX(r, f) ((r) * HS + ((((f) >> 2) ^ (((r) >> 2) & 15)) << 2))

// ---------------- K1: h = x @ W  (proven) + optional zeroing (fallback path) ----------------
__global__ __launch_bounds__(256) void gat_xw(const float* __restrict__ x,
                                              const float* __restrict__ W,
                                              float* __restrict__ h,
                                              float* __restrict__ z) {
    const int gt = blockIdx.x * 256 + threadIdx.x;
    if (z != nullptr && gt < ZTOT) z[gt] = 0.f;

    __shared__ float part[2][2][FO];
    const int wave = threadIdx.x >> 6;
    const int lane = threadIdx.x & 63;
    const int rs = wave >> 1;
    const int kh = wave & 1;
    int row = blockIdx.x * 2 + rs;
    row = __builtin_amdgcn_readfirstlane(row);
    const float* xr = x + (size_t)row * FIN + kh * (FIN / 2);
    const float* Wp = W + (size_t)kh * (FIN / 2) * FO;
    float acc = 0.f;
#pragma unroll 2
    for (int k = 0; k < FIN / 2; k += 8) {
        float4 xa = *(const float4*)(xr + k);
        float4 xb = *(const float4*)(xr + k + 4);
        acc = fmaf(xa.x, Wp[(k + 0) * FO + lane], acc);
        acc = fmaf(xa.y, Wp[(k + 1) * FO + lane], acc);
        acc = fmaf(xa.z, Wp[(k + 2) * FO + lane], acc);
        acc = fmaf(xa.w, Wp[(k + 3) * FO + lane], acc);
        acc = fmaf(xb.x, Wp[(k + 4) * FO + lane], acc);
        acc = fmaf(xb.y, Wp[(k + 5) * FO + lane], acc);
        acc = fmaf(xb.z, Wp[(k + 6) * FO + lane], acc);
        acc = fmaf(xb.w, Wp[(k + 7) * FO + lane], acc);
    }
    part[rs][kh][lane] = acc;
    __syncthreads();
    if (threadIdx.x < 128) {
        const int r2 = threadIdx.x >> 6;
        const int l2 = threadIdx.x & 63;
        h[((size_t)blockIdx.x * 2 + r2) * FO + l2] = part[r2][0][l2] + part[r2][1][l2];
    }
}

// ---------------- K2: register-tiled e + fixed-shift p + fused PV ----------------
// Structure identical to the round-2-proven kernel (same barriers, same lane maps,
// launch_bounds(256,4), unroll 4). Only the hi/hj LDS layout changed: stride-68
// 16B-aligned rows + f4 XOR swizzle -> all accesses are ds_read_b128/ds_write_b128
// at the bank-conflict floor. Total DS instrs per lane ~476 -> ~280.
template <bool ATOMIC>
__global__ __launch_bounds__(256, 4) void gat_attn(const float* __restrict__ h,
                                                   const int* __restrict__ adj,
                                                   const float* __restrict__ a,
                                                   float* __restrict__ po,
                                                   float* __restrict__ pl) {
    __shared__ __align__(16) float up[64 * PTS];   // union: hi_s (HX layout) / pT_s (plain 68)
    __shared__ __align__(16) float hj_s[64 * HS];
    __shared__ __align__(16) float a_s[FO];
    float* hi_s = up;
    float* pT_s = up;

    const int tid = threadIdx.x;
    const int w = tid >> 6;
    const int lane = tid & 63;
    const int li = lane & 3;
    const int lj = lane >> 2;
    const int it = blockIdx.x >> 5;          // 0..31
    const int jt = blockIdx.x & (NJT - 1);   // 0..31
    const int ib = it * 64;
    const int jb = jt * JR;
    const int iw = w * 16;

    // stage hi and hj tiles (64 x 64 each) -- pure float4, swizzled dest
    for (int g4 = tid; g4 < 1024; g4 += 256) {
        const int row = g4 >> 4;
        const int f0 = (g4 & 15) * 4;
        float4 v = *(const float4*)(h + (size_t)ib * FO + (size_t)g4 * 4);
        *(float4*)&hi_s[HX(row, f0)] = v;
        float4 u = *(const float4*)(h + (size_t)jb * FO + (size_t)g4 * 4);
        *(float4*)&hj_s[HX(row, f0)] = u;
    }
    if (tid < FO) a_s[tid] = a[tid];
    __syncthreads();

    // adjacency for this lane's 4x4 (16B-aligned)
    int4 am[4];
#pragma unroll
    for (int di = 0; di < 4; di++)
        am[di] = *(const int4*)(adj + (size_t)(ib + iw + 4 * li + di) * Nn + (jb + 4 * lj));

    float pv[4][4];
    float ls[4];
#pragma unroll
    for (int u = 0; u < 4; u++) {
        ls[u] = 0.f;
#pragma unroll
        for (int v2 = 0; v2 < 4; v2++) pv[u][v2] = 0.f;
    }

    // ---- e-phase: e[di][dj] = sum_f a_f * |hi - hj|, f-step 4, all b128 ----
    float e[4][4];
#pragma unroll
    for (int di = 0; di < 4; di++)
#pragma unroll
        for (int dj = 0; dj < 4; dj++) e[di][dj] = 0.f;

#pragma unroll 4
    for (int f = 0; f < FO; f += 4) {
        const float4 av = *(const float4*)&a_s[f];
        float4 hi4[4], hj4[4];
#pragma unroll
        for (int d = 0; d < 4; d++) {
            hi4[d] = *(const float4*)&hi_s[HX(iw + 4 * li + d, f)];
            hj4[d] = *(const float4*)&hj_s[HX(4 * lj + d, f)];
        }
#pragma unroll
        for (int di = 0; di < 4; di++)
#pragma unroll
            for (int dj = 0; dj < 4; dj++) {
                e[di][dj] = fmaf(fabsf(hi4[di].x - hj4[dj].x), av.x, e[di][dj]);
                e[di][dj] = fmaf(fabsf(hi4[di].y - hj4[dj].y), av.y, e[di][dj]);
                e[di][dj] = fmaf(fabsf(hi4[di].z - hj4[dj].z), av.z, e[di][dj]);
                e[di][dj] = fmaf(fabsf(hi4[di].w - hj4[dj].w), av.w, e[di][dj]);
            }
    }

    // ---- p = adj ? exp(relu(e) - SHIFT) : 0  (shift-invariant softmax, exact) ----
#pragma unroll
    for (int di = 0; di < 4; di++) {
        const int* ap = (const int*)&am[di];
#pragma unroll
        for (int dj = 0; dj < 4; dj++) {
            const float p = (ap[dj] > 0) ? __expf(fmaxf(e[di][dj], 0.f) - SHIFT) : 0.f;
            e[di][dj] = p;
            ls[di] += p;
        }
    }

    // all waves must be done reading hi_s before pT overwrites it (union)
    __syncthreads();

    // transpose p through pT (wave-private column slice [iw, iw+16))
#pragma unroll
    for (int dj = 0; dj < 4; dj++) {
        *(float4*)&pT_s[(4 * lj + dj) * PTS + iw + 4 * li] =
            make_float4(e[0][dj], e[1][dj], e[2][dj], e[3][dj]);
    }
    __syncthreads();   // order pT writes before PV reads

    // ---- PV: lane -> (4i x 4f): i = iw+4*li+di, f = 4*lj+v ; 2 b128 reads per j ----
#pragma unroll 4
    for (int j = 0; j < 64; j++) {
        const float4 pj = *(const float4*)&pT_s[j * PTS + iw + 4 * li];
        const float4 hv = *(const float4*)&hj_s[HX(j, 4 * lj)];
        pv[0][0] = fmaf(pj.x, hv.x, pv[0][0]);
        pv[0][1] = fmaf(pj.x, hv.y, pv[0][1]);
        pv[0][2] = fmaf(pj.x, hv.z, pv[0][2]);
        pv[0][3] = fmaf(pj.x, hv.w, pv[0][3]);
        pv[1][0] = fmaf(pj.y, hv.x, pv[1][0]);
        pv[1][1] = fmaf(pj.y, hv.y, pv[1][1]);
        pv[1][2] = fmaf(pj.y, hv.z, pv[1][2]);
        pv[1][3] = fmaf(pj.y, hv.w, pv[1][3]);
        pv[2][0] = fmaf(pj.z, hv.x, pv[2][0]);
        pv[2][1] = fmaf(pj.z, hv.y, pv[2][1]);
        pv[2][2] = fmaf(pj.z, hv.z, pv[2][2]);
        pv[2][3] = fmaf(pj.z, hv.w, pv[2][3]);
        pv[3][0] = fmaf(pj.w, hv.x, pv[3][0]);
        pv[3][1] = fmaf(pj.w, hv.y, pv[3][1]);
        pv[3][2] = fmaf(pj.w, hv.z, pv[3][2]);
        pv[3][3] = fmaf(pj.w, hv.w, pv[3][3]);
    }

    // ---- epilogue: reduce l over lj lanes ----
#pragma unroll
    for (int di = 0; di < 4; di++) {
        float v = ls[di];
        v += __shfl_xor(v, 4, 64);
        v += __shfl_xor(v, 8, 64);
        v += __shfl_xor(v, 16, 64);
        v += __shfl_xor(v, 32, 64);
        ls[di] = v;
    }

    if constexpr (!ATOMIC) {
        if (lj == 0) {
#pragma unroll
            for (int di = 0; di < 4; di++)
                pl[(size_t)jt * Nn + (ib + iw + 4 * li + di)] = ls[di];
        }
#pragma unroll
        for (int di = 0; di < 4; di++)
            *(float4*)&po[((size_t)jt * Nn + (ib + iw + 4 * li + di)) * FO + 4 * lj] =
                make_float4(pv[di][0], pv[di][1], pv[di][2], pv[di][3]);
    } else {
        if (lj == 0) {
#pragma unroll
            for (int di = 0; di < 4; di++)
                atomicAdd(&pl[ib + iw + 4 * li + di], ls[di]);
        }
#pragma unroll
        for (int di = 0; di < 4; di++) {
#pragma unroll
            for (int v2 = 0; v2 < 4; v2++)
                atomicAdd(&po[(size_t)(ib + iw + 4 * li + di) * FO + 4 * lj + v2], pv[di][v2]);
        }
    }
}

// ---------------- K3: out = relu(sum_jt po / sum_jt pl) ----------------
__global__ __launch_bounds__(256) void gat_reduce(const float* __restrict__ po,
                                                  const float* __restrict__ pl,
                                                  float* __restrict__ out) {
    const int t = blockIdx.x * 256 + threadIdx.x;   // grid 512 -> 131072 = Nn*FO
    const int i = t >> 6;
    float s = 0.f;
#pragma unroll
    for (int p = 0; p < NJT; p++) s += po[(size_t)p * (Nn * FO) + t];
    float l = 0.f;
#pragma unroll
    for (int p = 0; p < NJT; p++) l += pl[p * Nn + i];   // wave-uniform addr -> broadcast
    out[t] = fmaxf(s / l, 0.f);
}

// ---------------- fallback K3: out = relu(osum / lsum) ----------------
__global__ __launch_bounds__(256) void gat_fin(const float* __restrict__ osum,
                                               const float* __restrict__ lsum,
                                               float* __restrict__ out) {
    const int t = blockIdx.x * 256 + threadIdx.x;
    out[t] = fmaxf(osum[t] / lsum[t >> 6], 0.f);
}

extern "C" void kernel_launch(void* const* d_in, const int* in_sizes, int n_in,
                              void* d_out, int out_size, void* d_ws, size_t ws_size,
                              hipStream_t stream) {
    const float* x   = (const float*)d_in[0];
    const int*   adj = (const int*)d_in[1];
    const float* W   = (const float*)d_in[2];
    const float* a   = (const float*)d_in[3];
    float* out = (float*)d_out;

    float* h = (float*)d_ws;                                   // Nn*FO floats
    const size_t need = ((size_t)Nn * FO + (size_t)NJT * Nn * FO + (size_t)NJT * Nn) * 4;

    if (ws_size >= need) {
        // no-atomic path: private partials + reduction
        float* po = h + (size_t)Nn * FO;                       // NJT*Nn*FO floats
        float* pl = po + (size_t)NJT * Nn * FO;                // NJT*Nn floats
        gat_xw<<<dim3(1024), dim3(256), 0, stream>>>(x, W, h, nullptr);
        gat_attn<false><<<dim3(32 * NJT), dim3(256), 0, stream>>>(h, adj, a, po, pl);
        gat_reduce<<<dim3(512), dim3(256), 0, stream>>>(po, pl, out);
    } else {
        // fallback: atomic accumulation (1.06 MB workspace)
        float* osum = h + (size_t)Nn * FO;
        float* lsum = osum + (size_t)Nn * FO;
        gat_xw<<<dim3(1024), dim3(256), 0, stream>>>(x, W, h, osum);   // zeros osum+lsum
        gat_attn<true><<<dim3(32 * NJT), dim3(256), 0, stream>>>(h, adj, a, osum, lsum);
        gat_fin<<<dim3(512), dim3(256), 0, stream>>>(osum, lsum, out);
    }
}